// Round 9
// baseline (354.224 us; speedup 1.0000x reference)
//
#include <hip/hip_runtime.h>
#include <hip/hip_bf16.h>
#include <hip/hip_fp16.h>

constexpr int B = 8, C = 128, H = 80, W = 80, O = 128;
constexpr int HW = H * W;              // 6400
constexpr int NPIX = B * HW;           // 51200
constexpr int KC = C * 9;              // 1152
constexpr int DPX = 64;                // pixels per block (dcn kernel)
constexpr int NBLK = NPIX / DPX;       // 800

typedef _Float16 h8 __attribute__((ext_vector_type(8)));
typedef _Float16 h2 __attribute__((ext_vector_type(2)));
typedef float f32x4 __attribute__((ext_vector_type(4)));

__device__ inline h8 as_h8(uint4 v) { h8 r; __builtin_memcpy(&r, &v, 16); return r; }
__device__ inline h2 u2h(uint u) { h2 r; __builtin_memcpy(&r, &u, 4); return r; }
__device__ inline uint h2u(h2 h) { uint r; __builtin_memcpy(&r, &h, 4); return r; }
__device__ inline uint pkh(float a, float b) {
  h2 h = { (_Float16)a, (_Float16)b };
  return h2u(h);
}

// ------- kernel 0a: x [B][C][HW] fp32 -> xt [B][HW][C] fp16 (LDS transpose) -
__global__ __launch_bounds__(256) void k_xt(const float* __restrict__ x,
                                            _Float16* __restrict__ xt) {
  __shared__ uint tile32[64 * 64];   // [hw][c-pair], swizzled rows (16KB)
  const int t = threadIdx.x;
  const int p0 = blockIdx.x * 64;
  const int b = p0 / HW, hw0 = p0 - b * HW;
  const int w = t >> 6, l = t & 63;
#pragma unroll
  for (int j = 0; j < 16; ++j) {
    int c0 = (j * 4 + w) * 2;
    float f0 = x[((size_t)(b * C + c0)) * HW + hw0 + l];
    float f1 = x[((size_t)(b * C + c0 + 1)) * HW + hw0 + l];
    int byte = l * 256 + ((c0 * 2) ^ ((l & 7) << 4));
    tile32[byte >> 2] = pkh(f0, f1);
  }
  __syncthreads();
  _Float16* dst = xt + (size_t)(b * HW + hw0) * C;
#pragma unroll
  for (int it = 0; it < 4; ++it) {
    int g = w * 4096 + it * 1024 + l * 16;
    int row = g >> 8, inner = g & 255;
    uint4 v = *(const uint4*)((const char*)tile32 + row * 256 + (inner ^ ((row & 7) << 4)));
    *(uint4*)(dst + (g >> 1)) = v;
  }
}

// ------- kernel 0b: weight transforms, k-major fp16; zero zrow --------------
__global__ __launch_bounds__(256) void k_wt2(const float* __restrict__ w_dcn,
                                             const float* __restrict__ w_off,
                                             _Float16* __restrict__ wt,
                                             _Float16* __restrict__ wof,
                                             _Float16* __restrict__ zrow) {
  int i = blockIdx.x * 256 + threadIdx.x;
  if (i < O * KC) {
    int c = i & 127, k = (i >> 7) % 9, o = i / KC;
    wt[i] = (_Float16)w_dcn[(size_t)o * KC + c * 9 + k];
  }
  if (i < 32 * KC) {
    int c = i & 127, k = (i >> 7) % 9, o = i / KC;
    wof[i] = (o < 27) ? (_Float16)w_off[((size_t)o * C + c) * 9 + k] : (_Float16)0.f;
  }
  if (i < 128) zrow[i] = (_Float16)0.f;
}

// ------- kernel 1: offset conv via MFMA, NO LDS (B read direct from L2) -----
__global__ __launch_bounds__(256, 6) void k_offc4(
    const _Float16* __restrict__ xt, const _Float16* __restrict__ wof,
    const _Float16* __restrict__ zrow, const float* __restrict__ b_off,
    float* __restrict__ om) {
  const int t = threadIdx.x;
  const int bid = (blockIdx.x & 7) * 200 + (blockIdx.x >> 3);  // XCD chunking
  const int b = bid / 200, hw0 = (bid - b * 200) * 32;
  const int lane = t & 63, wv = t >> 6, rl = lane & 15, gh = lane >> 4;
  const int mi = wv & 1, nt = wv >> 1;
  const int px = hw0 + nt * 16 + rl;
  const int hp = px / W, wp = px - hp * W;
  const _Float16* xb = xt + (size_t)b * HW * C;
  f32x4 acc = {0.f, 0.f, 0.f, 0.f};
#pragma unroll
  for (int k = 0; k < 9; ++k) {
    int ky = k / 3, kx = k - ky * 3;
    int y = hp + ky - 1, xx = wp + kx - 1;
    bool ok = ((unsigned)y < (unsigned)H) && ((unsigned)xx < (unsigned)W);
    const _Float16* rowp = ok ? (xb + (size_t)(y * W + xx) * C) : zrow;
    const _Float16* aP = wof + (size_t)(mi * 16 + rl) * KC + k * 128 + gh * 8;
#pragma unroll
    for (int kk = 0; kk < 4; ++kk) {
      h8 av = *(const h8*)(aP + kk * 32);
      h8 bv = *(const h8*)(rowp + kk * 32 + gh * 8);
      acc = __builtin_amdgcn_mfma_f32_16x16x32_f16(av, bv, acc, 0, 0, 0);
    }
  }
  float* ob = om + (size_t)b * 27 * HW + hw0 + nt * 16 + rl;
#pragma unroll
  for (int r = 0; r < 4; ++r) {
    int oc = mi * 16 + gh * 4 + r;
    if (oc < 27) ob[(size_t)oc * HW] = acc[r] + b_off[oc];
  }
}

// ------- kernel 2: wave-autonomous gather + reg-interp + MFMA ---------------
// 256 thr = 4 waves, 64 px/block; each wave owns 16 px fully (all 128 outs).
// No per-tap barrier, no sampled-LDS: B-frags built in registers.
__global__ __launch_bounds__(256, 2) void k_dcn5(
    const _Float16* __restrict__ xt, const float* __restrict__ om,
    const _Float16* __restrict__ wt, float* __restrict__ outr,
    float* __restrict__ part2) {
  __shared__ float s_w[DPX][9][4];
  __shared__ int s_i[DPX][9][4];
  __shared__ float s_red[2][128][4];
  const int t = threadIdx.x;
  const int bid = (blockIdx.x & 7) * 100 + (blockIdx.x >> 3);  // XCD chunking
  const int b = bid / 100, hw0 = (bid - b * 100) * DPX;

  // metadata: 64 px x 9 taps (mask folded into corner weights)
  for (int idx = t; idx < DPX * 9; idx += 256) {
    int px = idx / 9, k = idx - (idx / 9) * 9;
    int hw = hw0 + px, h = hw / W, w = hw - (hw / W) * W;
    int ky = k / 3, kx = k - ky * 3;
    const float* omp = om + (size_t)b * 27 * HW + hw;
    float dy = omp[(size_t)(2 * k) * HW];
    float dx = omp[(size_t)(2 * k + 1) * HW];
    float mk = 1.0f / (1.0f + __expf(-omp[(size_t)(18 + k) * HW]));
    float py = dy + (float)(h - 1 + ky);
    float pxf = dx + (float)(w - 1 + kx);
    float y0f = floorf(py), x0f = floorf(pxf);
    float wy1 = py - y0f, wx1 = pxf - x0f;
    float wy0 = 1.0f - wy1, wx0 = 1.0f - wx1;
    int y0 = (int)y0f, x0 = (int)x0f;
    int y1 = y0 + 1, x1 = x0 + 1;
    bool vy0 = (y0 >= 0) && (y0 < H);
    bool vy1 = (y1 >= 0) && (y1 < H);
    bool vx0 = (x0 >= 0) && (x0 < W);
    bool vx1 = (x1 >= 0) && (x1 < W);
    int cy0 = min(max(y0, 0), H - 1), cy1 = min(max(y1, 0), H - 1);
    int cx0 = min(max(x0, 0), W - 1), cx1 = min(max(x1, 0), W - 1);
    s_w[px][k][0] = (vy0 && vx0) ? wy0 * wx0 * mk : 0.0f;
    s_w[px][k][1] = (vy0 && vx1) ? wy0 * wx1 * mk : 0.0f;
    s_w[px][k][2] = (vy1 && vx0) ? wy1 * wx0 * mk : 0.0f;
    s_w[px][k][3] = (vy1 && vx1) ? wy1 * wx1 * mk : 0.0f;
    s_i[px][k][0] = cy0 * W + cx0;
    s_i[px][k][1] = cy0 * W + cx1;
    s_i[px][k][2] = cy1 * W + cx0;
    s_i[px][k][3] = cy1 * W + cx1;
  }
  __syncthreads();

  const int lane = t & 63, wv = t >> 6, rl = lane & 15, gh = lane >> 4;
  const int mypx = wv * 16 + rl;                 // this lane's pixel (B-col)
  const _Float16* xb = xt + (size_t)b * HW * C + gh * 8;  // + k-chunk offset

  // pinned corner loads: 16 uint4 (corner-major, kstep minor via offset:)
  uint4 pa0, pa1, pa2, pa3, pb0, pb1, pb2, pb3;
  uint4 pc0, pc1, pc2, pc3, pd0, pd1, pd2, pd3;
  float4 wf;                                      // current tap's corner wts

#define GLD4(o0, o1, o2, o3, P)                                           \
  asm volatile("global_load_dwordx4 %0, %4, off\n\t"                     \
               "global_load_dwordx4 %1, %4, off offset:64\n\t"           \
               "global_load_dwordx4 %2, %4, off offset:128\n\t"          \
               "global_load_dwordx4 %3, %4, off offset:192"              \
               : "=&v"(o0), "=&v"(o1), "=&v"(o2), "=&v"(o3) : "v"(P))

  auto ISSUE = [&](int k) {
    int4 ii = *(const int4*)&s_i[mypx][k][0];
    wf = *(const float4*)&s_w[mypx][k][0];
    GLD4(pa0, pa1, pa2, pa3, xb + (size_t)ii.x * C);
    GLD4(pb0, pb1, pb2, pb3, xb + (size_t)ii.y * C);
    GLD4(pc0, pc1, pc2, pc3, xb + (size_t)ii.z * C);
    GLD4(pd0, pd1, pd2, pd3, xb + (size_t)ii.w * C);
  };

  f32x4 acc[8];
#pragma unroll
  for (int m = 0; m < 8; ++m) acc[m] = {0.f, 0.f, 0.f, 0.f};

  ISSUE(0);
  __builtin_amdgcn_sched_barrier(0);

  for (int k = 0; k < 9; ++k) {
    h2 W0 = {(_Float16)wf.x, (_Float16)wf.x};
    h2 W1 = {(_Float16)wf.y, (_Float16)wf.y};
    h2 W2 = {(_Float16)wf.z, (_Float16)wf.z};
    h2 W3 = {(_Float16)wf.w, (_Float16)wf.w};
    uint4 bf0, bf1, bf2, bf3;

    asm volatile("s_waitcnt vmcnt(8)" ::: "memory");   // y0 corners done
    __builtin_amdgcn_sched_barrier(0);
#define I1(DST, A, Bq)                                                    \
  DST.x = h2u(u2h(A.x) * W0 + u2h(Bq.x) * W1);                            \
  DST.y = h2u(u2h(A.y) * W0 + u2h(Bq.y) * W1);                            \
  DST.z = h2u(u2h(A.z) * W0 + u2h(Bq.z) * W1);                            \
  DST.w = h2u(u2h(A.w) * W0 + u2h(Bq.w) * W1);
    I1(bf0, pa0, pb0) I1(bf1, pa1, pb1) I1(bf2, pa2, pb2) I1(bf3, pa3, pb3)
#undef I1
    asm volatile("s_waitcnt vmcnt(0)" ::: "memory");   // y1 corners done
    __builtin_amdgcn_sched_barrier(0);
#define I2(DST, Cq, D)                                                    \
  DST.x = h2u(u2h(DST.x) + u2h(Cq.x) * W2 + u2h(D.x) * W3);               \
  DST.y = h2u(u2h(DST.y) + u2h(Cq.y) * W2 + u2h(D.y) * W3);               \
  DST.z = h2u(u2h(DST.z) + u2h(Cq.z) * W2 + u2h(D.z) * W3);               \
  DST.w = h2u(u2h(DST.w) + u2h(Cq.w) * W2 + u2h(D.w) * W3);
    I2(bf0, pc0, pd0) I2(bf1, pc1, pd1) I2(bf2, pc2, pd2) I2(bf3, pc3, pd3)
#undef I2
    __builtin_amdgcn_sched_barrier(0);

    // COMP: clean queue — compiler schedules A-frag loads (L1-hot) freely
    h8 b0 = as_h8(bf0), b1 = as_h8(bf1), b2 = as_h8(bf2), b3 = as_h8(bf3);
    __builtin_amdgcn_s_setprio(1);
#pragma unroll
    for (int m = 0; m < 8; ++m) {
      const _Float16* ap = wt + (size_t)(m * 16 + rl) * KC + k * 128 + gh * 8;
      acc[m] = __builtin_amdgcn_mfma_f32_16x16x32_f16(*(const h8*)(ap), b0, acc[m], 0, 0, 0);
      acc[m] = __builtin_amdgcn_mfma_f32_16x16x32_f16(*(const h8*)(ap + 32), b1, acc[m], 0, 0, 0);
      acc[m] = __builtin_amdgcn_mfma_f32_16x16x32_f16(*(const h8*)(ap + 64), b2, acc[m], 0, 0, 0);
      acc[m] = __builtin_amdgcn_mfma_f32_16x16x32_f16(*(const h8*)(ap + 96), b3, acc[m], 0, 0, 0);
    }
    __builtin_amdgcn_s_setprio(0);
    __builtin_amdgcn_sched_barrier(0);
    if (k < 8) {
      ISSUE(k + 1);                                   // latency spans backedge
      __builtin_amdgcn_sched_barrier(0);
    }
  }
#undef GLD4

  // C-write + per-wave BN sums (col = px = rl), then cross-wave LDS reduce
  float* outb = outr + (size_t)b * O * HW + hw0 + wv * 16 + rl;
#pragma unroll
  for (int m = 0; m < 8; ++m)
#pragma unroll
    for (int r = 0; r < 4; ++r) {
      int o = m * 16 + gh * 4 + r;
      float v = acc[m][r];
      outb[(size_t)o * HW] = v;
      float s = v, s2 = v * v;
#pragma unroll
      for (int mm = 1; mm < 16; mm <<= 1) {
        s += __shfl_xor(s, mm);
        s2 += __shfl_xor(s2, mm);
      }
      if (rl == 0) {
        s_red[0][o][wv] = s;
        s_red[1][o][wv] = s2;
      }
    }
  __syncthreads();
  if (t < 256) {
    int o = t & 127, st = t >> 7;
    float s = s_red[st][o][0] + s_red[st][o][1] + s_red[st][o][2] + s_red[st][o][3];
    part2[(size_t)(2 * o + st) * NBLK + blockIdx.x] = s;
  }
}

// ------- kernel 3: reduce per-block partials -> stats[256] ------------------
__global__ __launch_bounds__(256) void k_bnred(const float* __restrict__ part2,
                                               float* __restrict__ stats) {
  const int j = blockIdx.x;          // 0..255 = 2*o + stat
  float s = 0.f;
  for (int i = threadIdx.x; i < NBLK; i += 256) s += part2[(size_t)j * NBLK + i];
#pragma unroll
  for (int off = 32; off > 0; off >>= 1) s += __shfl_down(s, off);
  __shared__ float rs[4];
  int wid = threadIdx.x >> 6, lane = threadIdx.x & 63;
  if (lane == 0) rs[wid] = s;
  __syncthreads();
  if (threadIdx.x == 0) stats[j] = rs[0] + rs[1] + rs[2] + rs[3];
}

// ------- kernel 4: BN finalize + affine + SiLU, in place on d_out -----------
__global__ __launch_bounds__(256) void k_bnapply2(
    float* __restrict__ outr, const float* __restrict__ stats,
    const float* __restrict__ gamma, const float* __restrict__ beta) {
  const int n4 = B * O * HW / 4;
  for (int i = blockIdx.x * blockDim.x + threadIdx.x; i < n4;
       i += gridDim.x * blockDim.x) {
    int o = (i / (HW / 4)) % O;
    float S = stats[2 * o], S2 = stats[2 * o + 1];
    const float inv = 1.0f / (float)(B * HW);
    float mu = S * inv;
    float rstd = rsqrtf(fmaf(S2, inv, -mu * mu) + 1e-5f);
    float a = rstd * gamma[o];
    float bb = fmaf(-mu, a, beta[o]);
    float4 v = ((const float4*)outr)[i];
    float y0 = fmaf(v.x, a, bb);
    float y1 = fmaf(v.y, a, bb);
    float y2 = fmaf(v.z, a, bb);
    float y3 = fmaf(v.w, a, bb);
    v.x = y0 / (1.0f + __expf(-y0));
    v.y = y1 / (1.0f + __expf(-y1));
    v.z = y2 / (1.0f + __expf(-y2));
    v.w = y3 / (1.0f + __expf(-y3));
    ((float4*)outr)[i] = v;
  }
}

extern "C" void kernel_launch(void* const* d_in, const int* in_sizes, int n_in,
                              void* d_out, int out_size, void* d_ws, size_t ws_size,
                              hipStream_t stream) {
  const float* x = (const float*)d_in[0];
  const float* w_dcn = (const float*)d_in[1];
  // d_in[2] = b_dcn: per-channel constant, exactly cancelled by BN mean-sub.
  const float* w_off = (const float*)d_in[3];
  const float* b_off = (const float*)d_in[4];
  const float* gamma = (const float*)d_in[5];
  const float* beta = (const float*)d_in[6];
  float* out = (float*)d_out;
  // ws: om 5.53MB | xt 13.1MB | wt 288KB | wof 72KB | part2 800KB | stats | zrow
  float* om = (float*)d_ws;
  _Float16* xt = (_Float16*)(om + (size_t)B * 27 * HW);
  _Float16* wt = xt + (size_t)B * HW * C;
  _Float16* wof = wt + (size_t)O * KC;
  float* part2 = (float*)(wof + (size_t)32 * KC);
  float* stats = part2 + (size_t)256 * NBLK;
  _Float16* zrow = (_Float16*)(stats + 256);

  k_xt<<<NPIX / 64, 256, 0, stream>>>(x, xt);
  k_wt2<<<(O * KC + 255) / 256, 256, 0, stream>>>(w_dcn, w_off, wt, wof, zrow);
  k_offc4<<<NPIX / 32, 256, 0, stream>>>(xt, wof, zrow, b_off, om);
  k_dcn5<<<NBLK, 256, 0, stream>>>(xt, om, wt, out, part2);
  k_bnred<<<256, 256, 0, stream>>>(part2, stats);
  k_bnapply2<<<2048, 256, 0, stream>>>(out, stats, gamma, beta);
}